// Round 8
// baseline (315.241 us; speedup 1.0000x reference)
//
#include <hip/hip_runtime.h>
#include <hip/hip_bf16.h>
#include <stdint.h>

#define M_DIM 8192   // B*S
#define K_DIM 4096   // IN
#define N_DIM 4096   // OUT
#define NPIECE (K_DIM / 32)   // 128 K-pieces of 32

typedef __bf16 bf16x8v __attribute__((ext_vector_type(8)));
typedef float f32x16 __attribute__((ext_vector_type(16)));

__device__ __forceinline__ unsigned short f2bf(float f) {
    unsigned int u = __builtin_bit_cast(unsigned int, f);
    u += 0x7FFFu + ((u >> 16) & 1u);   // round-to-nearest-even
    return (unsigned short)(u >> 16);
}

// ---------- dequant: qweight [N][K/2] int32 (one packed byte each) -> W bf16 [N][K]
__global__ void k_dequant(const int4* __restrict__ qw4,
                          const float* __restrict__ scales,
                          const float* __restrict__ lut,
                          uint4* __restrict__ wb4) {
    __shared__ float sl[16];
    if (threadIdx.x < 16) sl[threadIdx.x] = lut[threadIdx.x];
    __syncthreads();
    int t = blockIdx.x * blockDim.x + threadIdx.x;   // exactly N*(K/2)/4 threads
    int4 q = qw4[t];
    int o = t >> 9;                   // row (512 int4 per row)
    int col0 = (t & 511) << 3;        // first of 8 output cols
    float s = scales[(o << 5) + (col0 >> 7)];   // GS=128
    int v[4] = {q.x, q.y, q.z, q.w};
    unsigned int pk[4];
#pragma unroll
    for (int j = 0; j < 4; ++j) {
        float w0 = sl[v[j] & 15] * s;          // low nibble first
        float w1 = sl[(v[j] >> 4) & 15] * s;
        pk[j] = (unsigned int)f2bf(w0) | ((unsigned int)f2bf(w1) << 16);
    }
    uint4 rr; rr.x = pk[0]; rr.y = pk[1]; rr.z = pk[2]; rr.w = pk[3];
    wb4[t] = rr;
}

// ---------- x f32 -> bf16
__global__ void k_cvt(const float4* __restrict__ x4, uint4* __restrict__ xb4) {
    int t = blockIdx.x * blockDim.x + threadIdx.x;   // exactly M*K/8 threads
    float4 a = x4[2 * t], b = x4[2 * t + 1];
    uint4 o;
    o.x = (unsigned int)f2bf(a.x) | ((unsigned int)f2bf(a.y) << 16);
    o.y = (unsigned int)f2bf(a.z) | ((unsigned int)f2bf(a.w) << 16);
    o.z = (unsigned int)f2bf(b.x) | ((unsigned int)f2bf(b.y) << 16);
    o.w = (unsigned int)f2bf(b.z) | ((unsigned int)f2bf(b.w) << 16);
    xb4[t] = o;
}

#define GLL16(SRC, DST)                                                              \
    __builtin_amdgcn_global_load_lds((__attribute__((address_space(1))) void*)(SRC), \
                                     (__attribute__((address_space(3))) void*)(DST), \
                                     16, 0, 0)

// ---------- GEMM: C[M][N] = Xb[M][K] * Wb[N][K]^T + bias
// Round-4 schedule (reg-fragment pipeline, 1 barrier/piece, 4 LDS slots,
// counted vmcnt(4)) with v_mfma_f32_32x32x16_bf16 fragments: per wave 128x64
// output = 4x2 frags of 32x32, 16 MFMA per 32-K piece (8 per half-piece).
__global__ __launch_bounds__(512, 2) void k_gemm(const __hip_bfloat16* __restrict__ A,
                                                 const __hip_bfloat16* __restrict__ Bw,
                                                 const float* __restrict__ bias,
                                                 float* __restrict__ C) {
    // slot: A piece [256 rows][32 K] bf16 (16KB) then B piece (16KB)
    __shared__ __align__(16) char lds[4][32768];   // 128 KiB

    const int tid  = threadIdx.x;
    const int lane = tid & 63;
    const int wave = tid >> 6;
    const int wm = wave >> 2;      // 0..1 -> M half (128 rows)
    const int wn = wave & 3;       // 0..3 -> N quarter (64 cols)
    const int bm = blockIdx.y, bn = blockIdx.x;

    f32x16 acc[4][2];
    const f32x16 z = {0.f};
#pragma unroll
    for (int i = 0; i < 4; ++i)
#pragma unroll
        for (int j = 0; j < 2; ++j) acc[i][j] = z;

    // ---- staging addresses (pre-swizzled per-lane global source, linear LDS dest)
    // each gll issue covers 8KB = 128 rows x 64B: thread t -> row t>>2, granule t&3
    const int trow = tid >> 2;                 // 0..127
    const int sg   = (tid & 3) ^ ((trow >> 1) & 3);   // swizzled source granule
    const char* aSrc = (const char*)A  + ((size_t)(bm * 256 + trow) * K_DIM) * 2 + sg * 16;
    const char* bSrc = (const char*)Bw + ((size_t)(bn * 256 + trow) * K_DIM) * 2 + sg * 16;
    const size_t hop = (size_t)128 * K_DIM * 2;   // +128 rows (second issue)
    const int woff = wave * 1024;                 // wave-uniform LDS dest base offset

    // ---- ds_read addresses (swizzled), 32x32x16 fragments
    // A frag fm, k-step ks: row = wm*128 + fm*32 + (lane&31), global granule ks*2+hi
    const int c31 = lane & 31;
    const int hi  = lane >> 5;
    const int swz = (c31 >> 1) & 3;                   // (row>>1)&3 (wm*128, fm*32 vanish mod 4)
    const int gk0 = ((0 + hi) ^ swz) * 16;            // ks=0 granule byte offset
    const int gk1 = ((2 + hi) ^ swz) * 16;            // ks=1
    const int aRowBase = (wm * 128 + c31) * 64;       // + fm*2048 + gk{0,1}
    const int bRowBase = 16384 + (wn * 64 + c31) * 64;// + fn*2048 + gk{0,1}

    bf16x8v aC[2][2], aN[2][2], bX[2][2], bY[2][2];   // [frag][ks]

#define STAGE_A(P)                                                           \
    do {                                                                     \
        char* d_ = (char*)lds[(P) & 3];                                      \
        const size_t ko_ = (size_t)(P) * 64;                                 \
        GLL16(aSrc + ko_,       d_ + 0    + woff);                           \
        GLL16(aSrc + hop + ko_, d_ + 8192 + woff);                           \
    } while (0)
#define STAGE_B(P)                                                           \
    do {                                                                     \
        char* d_ = (char*)lds[(P) & 3];                                      \
        const size_t ko_ = (size_t)(P) * 64;                                 \
        GLL16(bSrc + ko_,       d_ + 16384 + woff);                          \
        GLL16(bSrc + hop + ko_, d_ + 24576 + woff);                          \
    } while (0)

    // Piece body. aC holds frags {0,1} of P (loaded last piece), aN gets frags
    // {2,3} of P in HP0; HP1 refills aC/BNXT with piece P+1 frags.
#define PIECE_BODY(P, BCUR, BNXT, GLLON, RDNEXT, WAITSTR)                                              \
    do {                                                                                               \
        const char* slC_ = (const char*)&lds[0][0] + (((P) & 3) << 15);                                \
        const char* slN_ = (const char*)&lds[0][0] + ((((P) + 1) & 3) << 15);                          \
        /* HP0: read A frags 2,3 of P; issue stage(P+3); MFMA frags 0,1 */                             \
        _Pragma("unroll") for (int i = 0; i < 2; ++i) {                                                \
            aN[i][0] = *(const bf16x8v*)(slC_ + aRowBase + (i + 2) * 2048 + gk0);                      \
            aN[i][1] = *(const bf16x8v*)(slC_ + aRowBase + (i + 2) * 2048 + gk1);                      \
        }                                                                                              \
        if (GLLON) { STAGE_A((P) + 3); STAGE_B((P) + 3); }                                             \
        asm volatile("" ::: "memory");                                                                 \
        __builtin_amdgcn_s_setprio(1);                                                                 \
        _Pragma("unroll") for (int i = 0; i < 2; ++i)                                                  \
            _Pragma("unroll") for (int ks = 0; ks < 2; ++ks)                                           \
                _Pragma("unroll") for (int n = 0; n < 2; ++n)                                          \
                    acc[i][n] = __builtin_amdgcn_mfma_f32_32x32x16_bf16(aC[i][ks], BCUR[n][ks],        \
                                                                        acc[i][n], 0, 0, 0);           \
        __builtin_amdgcn_s_setprio(0);                                                                 \
        /* HP1: read piece P+1 frags 0,1 -> aC and B -> BNXT; MFMA frags 2,3 */                        \
        if (RDNEXT) {                                                                                  \
            _Pragma("unroll") for (int i = 0; i < 2; ++i) {                                            \
                aC[i][0] = *(const bf16x8v*)(slN_ + aRowBase + i * 2048 + gk0);                        \
                aC[i][1] = *(const bf16x8v*)(slN_ + aRowBase + i * 2048 + gk1);                        \
            }                                                                                          \
            _Pragma("unroll") for (int n = 0; n < 2; ++n) {                                            \
                BNXT[n][0] = *(const bf16x8v*)(slN_ + bRowBase + n * 2048 + gk0);                      \
                BNXT[n][1] = *(const bf16x8v*)(slN_ + bRowBase + n * 2048 + gk1);                      \
            }                                                                                          \
        }                                                                                              \
        asm volatile("" ::: "memory");                                                                 \
        __builtin_amdgcn_s_setprio(1);                                                                 \
        _Pragma("unroll") for (int i = 0; i < 2; ++i)                                                  \
            _Pragma("unroll") for (int ks = 0; ks < 2; ++ks)                                           \
                _Pragma("unroll") for (int n = 0; n < 2; ++n)                                          \
                    acc[i + 2][n] = __builtin_amdgcn_mfma_f32_32x32x16_bf16(aN[i][ks], BCUR[n][ks],    \
                                                                            acc[i + 2][n], 0, 0, 0);   \
        __builtin_amdgcn_s_setprio(0);                                                                 \
        asm volatile(WAITSTR ::: "memory");                                                            \
        __builtin_amdgcn_s_barrier();                                                                  \
        asm volatile("" ::: "memory");                                                                 \
    } while (0)

    // ---- prologue: stage pieces 0,1,2; wait for 0,1; preload piece-0 frags
    STAGE_A(0); STAGE_B(0);
    STAGE_A(1); STAGE_B(1);
    STAGE_A(2); STAGE_B(2);
    asm volatile("s_waitcnt vmcnt(4)" ::: "memory");   // stages 0,1 landed; 2 in flight
    __builtin_amdgcn_s_barrier();
    asm volatile("" ::: "memory");
#pragma unroll
    for (int i = 0; i < 2; ++i) {
        aC[i][0] = *(const bf16x8v*)((const char*)&lds[0][0] + aRowBase + i * 2048 + gk0);
        aC[i][1] = *(const bf16x8v*)((const char*)&lds[0][0] + aRowBase + i * 2048 + gk1);
    }
#pragma unroll
    for (int n = 0; n < 2; ++n) {
        bX[n][0] = *(const bf16x8v*)((const char*)&lds[0][0] + bRowBase + n * 2048 + gk0);
        bX[n][1] = *(const bf16x8v*)((const char*)&lds[0][0] + bRowBase + n * 2048 + gk1);
    }

    // ---- main loop: pieces 0..123 (B-role alternates by parity)
    for (int p = 0; p < NPIECE - 4; p += 2) {
        PIECE_BODY(p,     bX, bY, 1, 1, "s_waitcnt vmcnt(4)");
        PIECE_BODY(p + 1, bY, bX, 1, 1, "s_waitcnt vmcnt(4)");
    }
    // ---- tail: pieces 124..127 (stage(127) issued at 124; then drain)
    PIECE_BODY(124, bX, bY, 1, 1, "s_waitcnt vmcnt(4)");
    PIECE_BODY(125, bY, bX, 0, 1, "s_waitcnt vmcnt(0)");
    PIECE_BODY(126, bX, bY, 0, 1, "s_nop 0");
    PIECE_BODY(127, bY, bX, 0, 0, "s_nop 0");

#undef PIECE_BODY
#undef STAGE_A
#undef STAGE_B

    // ---- epilogue: 32x32 C/D layout col=lane&31, row=(reg&3)+8*(reg>>2)+4*(lane>>5)
    const int gr0 = bm * 256 + wm * 128;
    const int gc0 = bn * 256 + wn * 64;
    float bv[2];
#pragma unroll
    for (int n = 0; n < 2; ++n) bv[n] = bias[gc0 + n * 32 + c31];
#pragma unroll
    for (int fm = 0; fm < 4; ++fm)
#pragma unroll
        for (int j = 0; j < 16; ++j) {
            const int row = gr0 + fm * 32 + (j & 3) + 8 * (j >> 2) + 4 * hi;
            float* crow = C + (size_t)row * N_DIM + gc0 + c31;
            crow[0]  = acc[fm][0][j] + bv[0];
            crow[32] = acc[fm][1][j] + bv[1];
        }
}

// ---------- naive fallback (only if ws too small)
__global__ void k_naive(const float* __restrict__ x, const int* __restrict__ qw,
                        const float* __restrict__ scales, const float* __restrict__ bias,
                        const float* __restrict__ lut, float* __restrict__ y) {
    long t = (long)blockIdx.x * blockDim.x + threadIdx.x;
    if (t >= (long)M_DIM * N_DIM) return;
    int m = (int)(t / N_DIM), n = (int)(t % N_DIM);
    float acc = 0.f;
    for (int k = 0; k < K_DIM; k += 2) {
        int b = qw[n * (K_DIM / 2) + (k >> 1)];
        float s = scales[n * 32 + (k >> 7)];
        acc += x[(size_t)m * K_DIM + k]     * lut[b & 15]        * s;
        acc += x[(size_t)m * K_DIM + k + 1] * lut[(b >> 4) & 15] * s;
    }
    y[t] = acc + bias[n];
}

extern "C" void kernel_launch(void* const* d_in, const int* in_sizes, int n_in,
                              void* d_out, int out_size, void* d_ws, size_t ws_size,
                              hipStream_t stream) {
    const float* x      = (const float*)d_in[0];
    const int*   qw     = (const int*)d_in[1];
    const float* scales = (const float*)d_in[2];
    const float* bias   = (const float*)d_in[3];
    const float* lut    = (const float*)d_in[5];
    float* y = (float*)d_out;

    const size_t wbBytes = (size_t)N_DIM * K_DIM * 2;   // 32 MiB
    const size_t xbBytes = (size_t)M_DIM * K_DIM * 2;   // 64 MiB
    if (ws_size < wbBytes + xbBytes) {
        long total = (long)M_DIM * N_DIM;
        k_naive<<<(int)((total + 255) / 256), 256, 0, stream>>>(x, qw, scales, bias, lut, y);
        return;
    }
    __hip_bfloat16* Wb = (__hip_bfloat16*)d_ws;
    __hip_bfloat16* Xb = (__hip_bfloat16*)((char*)d_ws + wbBytes);

    k_dequant<<<N_DIM * (K_DIM / 2) / 4 / 256, 256, 0, stream>>>(
        (const int4*)qw, scales, lut, (uint4*)Wb);
    k_cvt<<<(int)((size_t)M_DIM * K_DIM / 8 / 256), 256, 0, stream>>>(
        (const float4*)x, (uint4*)Xb);
    dim3 grid(N_DIM / 256, M_DIM / 256);
    k_gemm<<<grid, 512, 0, stream>>>(Xb, Wb, bias, y);
}

// Round 10
// 314.023 us; speedup vs baseline: 1.0039x; 1.0039x over previous
//
#include <hip/hip_runtime.h>
#include <hip/hip_bf16.h>
#include <stdint.h>

#define M_DIM 8192   // B*S
#define K_DIM 4096   // IN
#define N_DIM 4096   // OUT
#define NPIECE (K_DIM / 32)   // 128 K-pieces of 32

typedef __bf16 bf16x8v __attribute__((ext_vector_type(8)));
typedef float f32x4 __attribute__((ext_vector_type(4)));

__device__ __forceinline__ unsigned short f2bf(float f) {
    unsigned int u = __builtin_bit_cast(unsigned int, f);
    u += 0x7FFFu + ((u >> 16) & 1u);   // round-to-nearest-even
    return (unsigned short)(u >> 16);
}

// ---------- dequant: qweight [N][K/2] int32 (one packed byte each) -> W bf16 [N][K]
__global__ void k_dequant(const int4* __restrict__ qw4,
                          const float* __restrict__ scales,
                          const float* __restrict__ lut,
                          uint4* __restrict__ wb4) {
    __shared__ float sl[16];
    if (threadIdx.x < 16) sl[threadIdx.x] = lut[threadIdx.x];
    __syncthreads();
    int t = blockIdx.x * blockDim.x + threadIdx.x;   // exactly N*(K/2)/4 threads
    int4 q = qw4[t];
    int o = t >> 9;                   // row (512 int4 per row)
    int col0 = (t & 511) << 3;        // first of 8 output cols
    float s = scales[(o << 5) + (col0 >> 7)];   // GS=128
    int v[4] = {q.x, q.y, q.z, q.w};
    unsigned int pk[4];
#pragma unroll
    for (int j = 0; j < 4; ++j) {
        float w0 = sl[v[j] & 15] * s;          // low nibble first
        float w1 = sl[(v[j] >> 4) & 15] * s;
        pk[j] = (unsigned int)f2bf(w0) | ((unsigned int)f2bf(w1) << 16);
    }
    uint4 rr; rr.x = pk[0]; rr.y = pk[1]; rr.z = pk[2]; rr.w = pk[3];
    wb4[t] = rr;
}

// ---------- x f32 -> bf16
__global__ void k_cvt(const float4* __restrict__ x4, uint4* __restrict__ xb4) {
    int t = blockIdx.x * blockDim.x + threadIdx.x;   // exactly M*K/8 threads
    float4 a = x4[2 * t], b = x4[2 * t + 1];
    uint4 o;
    o.x = (unsigned int)f2bf(a.x) | ((unsigned int)f2bf(a.y) << 16);
    o.y = (unsigned int)f2bf(a.z) | ((unsigned int)f2bf(a.w) << 16);
    o.z = (unsigned int)f2bf(b.x) | ((unsigned int)f2bf(b.y) << 16);
    o.w = (unsigned int)f2bf(b.z) | ((unsigned int)f2bf(b.w) << 16);
    xb4[t] = o;
}

#define GLL16(SRC, DST)                                                              \
    __builtin_amdgcn_global_load_lds((__attribute__((address_space(1))) void*)(SRC), \
                                     (__attribute__((address_space(3))) void*)(DST), \
                                     16, 0, 0)

// ---------- GEMM: C[M][N] = Xb[M][K] * Wb[N][K]^T + bias
// 256x128 tile, 256 threads (4 waves 2Mx2N, per-wave 128x64 = round-4 pattern),
// 3 LDS slots x 24KB (72KB -> 2 independent blocks/CU), stage+2 with counted
// vmcnt(6), 1 barrier per 32-K piece, round-4 XOR swizzle (zero conflicts).
__global__ __launch_bounds__(256, 2) void k_gemm(const __hip_bfloat16* __restrict__ A,
                                                 const __hip_bfloat16* __restrict__ Bw,
                                                 const float* __restrict__ bias,
                                                 float* __restrict__ C) {
    // slot s at s*24576: A piece [256 rows][64B] (16KB) then B piece [128 rows][64B] (8KB)
    __shared__ __align__(16) char lds[3][24576];   // 72 KiB

    const int tid  = threadIdx.x;
    const int lane = tid & 63;
    const int wave = tid >> 6;
    const int wm = wave >> 1;      // 0..1 -> M half (128 rows)
    const int wn = wave & 1;       // 0..1 -> N half (64 cols)
    const int bm = blockIdx.y, bn = blockIdx.x;

    f32x4 acc[8][4];
    const f32x4 z = {0.f, 0.f, 0.f, 0.f};
#pragma unroll
    for (int i = 0; i < 8; ++i)
#pragma unroll
        for (int j = 0; j < 4; ++j) acc[i][j] = z;

    // ---- staging (pre-swizzled per-lane global source, linear LDS dest)
    // one gll issue covers 4KB = 64 rows x 64B: thread t -> row t>>2, granule t&3
    const int trow = tid >> 2;                 // 0..63
    const int sg   = (tid & 3) ^ ((trow >> 1) & 3);   // swizzled source granule
    const char* aSrc = (const char*)A  + ((size_t)(bm * 256 + trow) * K_DIM) * 2 + sg * 16;
    const char* bSrc = (const char*)Bw + ((size_t)(bn * 128 + trow) * K_DIM) * 2 + sg * 16;
    const size_t hop = (size_t)64 * K_DIM * 2;    // +64 rows per issue
    const int woff = wave * 1024;                 // wave-uniform dest offset within 4KB issue
    char* ldsw = &lds[0][0];
    const char* ldsb = &lds[0][0];

    // ---- ds_read addresses (round-4 verified zero-conflict pattern)
    const int r   = lane & 15;
    const int kq  = lane >> 4;                  // K granule wanted
    const int gsw = kq ^ ((r >> 1) & 3);        // swizzled granule
    const int aOff = (wm * 128 + r) * 64 + gsw * 16;           // + m*1024
    const int bOff = 16384 + (wn * 64 + r) * 64 + gsw * 16;    // + n*1024

    bf16x8v aC[4], aN[4], bX[4];

    // stage piece P into slot SS (6 gll issues: 4 A + 2 B)
#define STAGE(P, SS)                                                         \
    do {                                                                     \
        char* d_ = ldsw + (SS) * 24576 + woff;                               \
        const size_t ko_ = (size_t)(P) * 64;                                 \
        GLL16(aSrc + ko_,           d_ + 0);                                 \
        GLL16(aSrc + hop + ko_,     d_ + 4096);                              \
        GLL16(aSrc + 2 * hop + ko_, d_ + 8192);                              \
        GLL16(aSrc + 3 * hop + ko_, d_ + 12288);                             \
        GLL16(bSrc + ko_,           d_ + 16384);                             \
        GLL16(bSrc + hop + ko_,     d_ + 20480);                             \
    } while (0)

    // piece body: reads (slot SC only), stage(P+2 -> slot SS), MFMA m0-3,
    // read aN under it, MFMA m4-7, counted wait, ONE barrier.
#define PIECE(P, SC, SS, GLLON, WAITSTR)                                                               \
    do {                                                                                               \
        const char* sl_ = ldsb + (SC) * 24576;                                                         \
        _Pragma("unroll") for (int m = 0; m < 4; ++m)                                                  \
            aC[m] = *(const bf16x8v*)(sl_ + aOff + m * 1024);                                          \
        _Pragma("unroll") for (int n = 0; n < 4; ++n)                                                  \
            bX[n] = *(const bf16x8v*)(sl_ + bOff + n * 1024);                                          \
        if (GLLON) STAGE((P) + 2, SS);                                                                 \
        asm volatile("" ::: "memory");                                                                 \
        __builtin_amdgcn_s_setprio(1);                                                                 \
        _Pragma("unroll") for (int m = 0; m < 4; ++m)                                                  \
            _Pragma("unroll") for (int n = 0; n < 4; ++n)                                              \
                acc[m][n] = __builtin_amdgcn_mfma_f32_16x16x32_bf16(aC[m], bX[n], acc[m][n], 0, 0, 0); \
        __builtin_amdgcn_s_setprio(0);                                                                 \
        _Pragma("unroll") for (int m = 0; m < 4; ++m)                                                  \
            aN[m] = *(const bf16x8v*)(sl_ + aOff + (m + 4) * 1024);                                    \
        asm volatile("" ::: "memory");                                                                 \
        __builtin_amdgcn_s_setprio(1);                                                                 \
        _Pragma("unroll") for (int m = 0; m < 4; ++m)                                                  \
            _Pragma("unroll") for (int n = 0; n < 4; ++n)                                              \
                acc[m + 4][n] =                                                                        \
                    __builtin_amdgcn_mfma_f32_16x16x32_bf16(aN[m], bX[n], acc[m + 4][n], 0, 0, 0);     \
        __builtin_amdgcn_s_setprio(0);                                                                 \
        asm volatile(WAITSTR ::: "memory");                                                            \
        __builtin_amdgcn_s_barrier();                                                                  \
        asm volatile("" ::: "memory");                                                                 \
    } while (0)

    // ---- prologue: stage pieces 0,1; counted wait (stage(1)'s 6 stay in flight)
    STAGE(0, 0);
    STAGE(1, 1);
    asm volatile("s_waitcnt vmcnt(6)" ::: "memory");
    __builtin_amdgcn_s_barrier();
    asm volatile("" ::: "memory");

    // ---- main loop: pieces 0..125 (42 x 3, slots rotate 0,1,2; stage slot = (P+2)%3)
    for (int p = 0; p < 126; p += 3) {
        PIECE(p,     0, 2, 1, "s_waitcnt vmcnt(6)");
        PIECE(p + 1, 1, 0, 1, "s_waitcnt vmcnt(6)");
        PIECE(p + 2, 2, 1, 1, "s_waitcnt vmcnt(6)");
    }
    // ---- tail: piece 126 (slot 0) drains stage(127); piece 127 (slot 1)
    PIECE(126, 0, 0, 0, "s_waitcnt vmcnt(0)");
    PIECE(127, 1, 0, 0, "s_nop 0");

#undef PIECE
#undef STAGE

    // ---- epilogue: C/D layout col=lane&15, row=(lane>>4)*4+j
    const int q   = lane >> 4;
    const int gr0 = bm * 256 + wm * 128;
    const int gc0 = bn * 128 + wn * 64 + r;
    float bv[4];
#pragma unroll
    for (int n = 0; n < 4; ++n) bv[n] = bias[gc0 + n * 16];
#pragma unroll
    for (int m = 0; m < 8; ++m)
#pragma unroll
        for (int j = 0; j < 4; ++j) {
            float* crow = C + (size_t)(gr0 + m * 16 + q * 4 + j) * N_DIM + gc0;
#pragma unroll
            for (int n = 0; n < 4; ++n)
                crow[n * 16] = acc[m][n][j] + bv[n];
        }
}

// ---------- naive fallback (only if ws too small)
__global__ void k_naive(const float* __restrict__ x, const int* __restrict__ qw,
                        const float* __restrict__ scales, const float* __restrict__ bias,
                        const float* __restrict__ lut, float* __restrict__ y) {
    long t = (long)blockIdx.x * blockDim.x + threadIdx.x;
    if (t >= (long)M_DIM * N_DIM) return;
    int m = (int)(t / N_DIM), n = (int)(t % N_DIM);
    float acc = 0.f;
    for (int k = 0; k < K_DIM; k += 2) {
        int b = qw[n * (K_DIM / 2) + (k >> 1)];
        float s = scales[n * 32 + (k >> 7)];
        acc += x[(size_t)m * K_DIM + k]     * lut[b & 15]        * s;
        acc += x[(size_t)m * K_DIM + k + 1] * lut[(b >> 4) & 15] * s;
    }
    y[t] = acc + bias[n];
}

extern "C" void kernel_launch(void* const* d_in, const int* in_sizes, int n_in,
                              void* d_out, int out_size, void* d_ws, size_t ws_size,
                              hipStream_t stream) {
    const float* x      = (const float*)d_in[0];
    const int*   qw     = (const int*)d_in[1];
    const float* scales = (const float*)d_in[2];
    const float* bias   = (const float*)d_in[3];
    const float* lut    = (const float*)d_in[5];
    float* y = (float*)d_out;

    const size_t wbBytes = (size_t)N_DIM * K_DIM * 2;   // 32 MiB
    const size_t xbBytes = (size_t)M_DIM * K_DIM * 2;   // 64 MiB
    if (ws_size < wbBytes + xbBytes) {
        long total = (long)M_DIM * N_DIM;
        k_naive<<<(int)((total + 255) / 256), 256, 0, stream>>>(x, qw, scales, bias, lut, y);
        return;
    }
    __hip_bfloat16* Wb = (__hip_bfloat16*)d_ws;
    __hip_bfloat16* Xb = (__hip_bfloat16*)((char*)d_ws + wbBytes);

    k_dequant<<<N_DIM * (K_DIM / 2) / 4 / 256, 256, 0, stream>>>(
        (const int4*)qw, scales, lut, (uint4*)Wb);
    k_cvt<<<(int)((size_t)M_DIM * K_DIM / 8 / 256), 256, 0, stream>>>(
        (const float4*)x, (uint4*)Xb);
    dim3 grid(N_DIM / 128, M_DIM / 256);
    k_gemm<<<grid, 256, 0, stream>>>(Xb, Wb, bias, y);
}

// Round 11
// 283.878 us; speedup vs baseline: 1.1105x; 1.1062x over previous
//
#include <hip/hip_runtime.h>
#include <hip/hip_bf16.h>
#include <stdint.h>

#define M_DIM 8192   // B*S
#define K_DIM 4096   // IN
#define N_DIM 4096   // OUT
#define NPIECE (K_DIM / 32)   // 128 K-pieces of 32

#define DQ_BLOCKS 8192    // N*(K/2)/4/256
#define CVT_BLOCKS 16384  // M*K/8/256

typedef __bf16 bf16x8v __attribute__((ext_vector_type(8)));
typedef float f32x4 __attribute__((ext_vector_type(4)));

__device__ __forceinline__ unsigned short f2bf(float f) {
    unsigned int u = __builtin_bit_cast(unsigned int, f);
    u += 0x7FFFu + ((u >> 16) & 1u);   // round-to-nearest-even
    return (unsigned short)(u >> 16);
}

// ---------- prep: blocks [0,DQ_BLOCKS) dequant qweight -> Wb; rest cvt x -> Xb
__global__ void k_prep(const int4* __restrict__ qw4,
                       const float* __restrict__ scales,
                       const float* __restrict__ lut,
                       uint4* __restrict__ wb4,
                       const float4* __restrict__ x4,
                       uint4* __restrict__ xb4) {
    if (blockIdx.x < DQ_BLOCKS) {
        __shared__ float sl[16];
        if (threadIdx.x < 16) sl[threadIdx.x] = lut[threadIdx.x];
        __syncthreads();
        int t = blockIdx.x * blockDim.x + threadIdx.x;   // N*(K/2)/4 threads
        int4 q = qw4[t];
        int o = t >> 9;                   // row (512 int4 per row)
        int col0 = (t & 511) << 3;        // first of 8 output cols
        float s = scales[(o << 5) + (col0 >> 7)];   // GS=128
        int v[4] = {q.x, q.y, q.z, q.w};
        unsigned int pk[4];
#pragma unroll
        for (int j = 0; j < 4; ++j) {
            float w0 = sl[v[j] & 15] * s;          // low nibble first
            float w1 = sl[(v[j] >> 4) & 15] * s;
            pk[j] = (unsigned int)f2bf(w0) | ((unsigned int)f2bf(w1) << 16);
        }
        uint4 rr; rr.x = pk[0]; rr.y = pk[1]; rr.z = pk[2]; rr.w = pk[3];
        wb4[t] = rr;
    } else {
        int t = (blockIdx.x - DQ_BLOCKS) * blockDim.x + threadIdx.x;   // M*K/8 threads
        float4 a = x4[2 * t], b = x4[2 * t + 1];
        uint4 o;
        o.x = (unsigned int)f2bf(a.x) | ((unsigned int)f2bf(a.y) << 16);
        o.y = (unsigned int)f2bf(a.z) | ((unsigned int)f2bf(a.w) << 16);
        o.z = (unsigned int)f2bf(b.x) | ((unsigned int)f2bf(b.y) << 16);
        o.w = (unsigned int)f2bf(b.z) | ((unsigned int)f2bf(b.w) << 16);
        xb4[t] = o;
    }
}

#define GLL16(SRC, DST)                                                              \
    __builtin_amdgcn_global_load_lds((__attribute__((address_space(1))) void*)(SRC), \
                                     (__attribute__((address_space(3))) void*)(DST), \
                                     16, 0, 0)

// ---------- GEMM: C[M][N] = Xb[M][K] * Wb[N][K]^T + bias
// Round-4 verified structure (237 us, MfmaUtil 55.9%, 0 conflicts):
// 256x256 tile, 8 waves (2Mx4N), K in 32-wide pieces, 4 LDS slots round-robin,
// register-fragment pipeline one half-piece ahead, ONE barrier per piece,
// counted vmcnt(4) boundaries, XOR-swizzled LDS (granule ^= (row>>1)&3).
__global__ __launch_bounds__(512, 2) void k_gemm(const __hip_bfloat16* __restrict__ A,
                                                 const __hip_bfloat16* __restrict__ Bw,
                                                 const float* __restrict__ bias,
                                                 float* __restrict__ C) {
    // slot: A piece [256 rows][32 K] bf16 (16KB) then B piece (16KB)
    __shared__ __align__(16) char lds[4][32768];   // 128 KiB

    const int tid  = threadIdx.x;
    const int lane = tid & 63;
    const int wave = tid >> 6;
    const int wm = wave >> 2;      // 0..1 -> M half
    const int wn = wave & 3;       // 0..3 -> N quarter
    const int bm = blockIdx.y, bn = blockIdx.x;

    f32x4 acc[8][4];
    const f32x4 z = {0.f, 0.f, 0.f, 0.f};
#pragma unroll
    for (int i = 0; i < 8; ++i)
#pragma unroll
        for (int j = 0; j < 4; ++j) acc[i][j] = z;

    // ---- staging addresses (pre-swizzled per-lane global source, linear LDS dest)
    const int trow = tid >> 2;                 // 0..127
    const int sg   = (tid & 3) ^ ((trow >> 1) & 3);   // swizzled source granule
    const char* aSrc = (const char*)A  + ((size_t)(bm * 256 + trow) * K_DIM) * 2 + sg * 16;
    const char* bSrc = (const char*)Bw + ((size_t)(bn * 256 + trow) * K_DIM) * 2 + sg * 16;
    const size_t hop = (size_t)128 * K_DIM * 2;   // +128 rows (second issue)
    const int woff = wave * 1024;                 // wave-uniform LDS dest base offset

    // ---- ds_read addresses (swizzled)
    const int r   = lane & 15;
    const int kq  = lane >> 4;                  // K granule wanted
    const int gsw = kq ^ ((r >> 1) & 3);        // swizzled granule
    const int aOff = (wm * 128 + r) * 64 + gsw * 16;           // + m*1024
    const int bOff = 16384 + (wn * 64 + r) * 64 + gsw * 16;    // + n*1024

    bf16x8v aC[4], aN[4], bX[4], bY[4];

#define STAGE_A(P)                                                           \
    do {                                                                     \
        char* d_ = (char*)lds[(P) & 3];                                      \
        const size_t ko_ = (size_t)(P) * 64;                                 \
        GLL16(aSrc + ko_,       d_ + 0    + woff);                           \
        GLL16(aSrc + hop + ko_, d_ + 8192 + woff);                           \
    } while (0)
#define STAGE_B(P)                                                           \
    do {                                                                     \
        char* d_ = (char*)lds[(P) & 3];                                      \
        const size_t ko_ = (size_t)(P) * 64;                                 \
        GLL16(bSrc + ko_,       d_ + 16384 + woff);                          \
        GLL16(bSrc + hop + ko_, d_ + 24576 + woff);                          \
    } while (0)

    // Piece body. BCUR = this piece's B frags (loaded last piece); BNXT gets next
    // piece's B. aC holds A0-3(P) (loaded last piece), aN gets A4-7(P) in HP0 and
    // is consumed in HP1; aC is refilled with A0-3(P+1) in HP1.
#define PIECE_BODY(P, BCUR, BNXT, GLLON, RDNEXT, WAITSTR)                                              \
    do {                                                                                               \
        const char* slC_ = (const char*)&lds[0][0] + (((P) & 3) << 15);                                \
        const char* slN_ = (const char*)&lds[0][0] + ((((P) + 1) & 3) << 15);                          \
        /* HP0: issue reads A4-7(P); issue stage(P+3); MFMA m0-3 on prior-loaded regs */               \
        _Pragma("unroll") for (int m = 0; m < 4; ++m)                                                  \
            aN[m] = *(const bf16x8v*)(slC_ + aOff + (m + 4) * 1024);                                   \
        if (GLLON) { STAGE_A((P) + 3); STAGE_B((P) + 3); }                                             \
        asm volatile("" ::: "memory");                                                                 \
        __builtin_amdgcn_s_setprio(1);                                                                 \
        _Pragma("unroll") for (int m = 0; m < 4; ++m)                                                  \
            _Pragma("unroll") for (int n = 0; n < 4; ++n)                                              \
                acc[m][n] = __builtin_amdgcn_mfma_f32_16x16x32_bf16(aC[m], BCUR[n], acc[m][n], 0, 0, 0); \
        __builtin_amdgcn_s_setprio(0);                                                                 \
        /* HP1: issue reads A0-3(P+1)->aC, B(P+1)->BNXT; MFMA m4-7 */                                  \
        if (RDNEXT) {                                                                                  \
            _Pragma("unroll") for (int m = 0; m < 4; ++m)                                              \
                aC[m] = *(const bf16x8v*)(slN_ + aOff + m * 1024);                                     \
            _Pragma("unroll") for (int n = 0; n < 4; ++n)                                              \
                BNXT[n] = *(const bf16x8v*)(slN_ + bOff + n * 1024);                                   \
        }                                                                                              \
        asm volatile("" ::: "memory");                                                                 \
        __builtin_amdgcn_s_setprio(1);                                                                 \
        _Pragma("unroll") for (int m = 0; m < 4; ++m)                                                  \
            _Pragma("unroll") for (int n = 0; n < 4; ++n)                                              \
                acc[m + 4][n] =                                                                        \
                    __builtin_amdgcn_mfma_f32_16x16x32_bf16(aN[m], BCUR[n], acc[m + 4][n], 0, 0, 0);   \
        __builtin_amdgcn_s_setprio(0);                                                                 \
        asm volatile(WAITSTR ::: "memory");                                                            \
        __builtin_amdgcn_s_barrier();                                                                  \
        asm volatile("" ::: "memory");                                                                 \
    } while (0)

    // ---- prologue: stage pieces 0,1,2; wait until stage(0),(1) landed; preload piece-0 regs
    STAGE_A(0); STAGE_B(0);
    STAGE_A(1); STAGE_B(1);
    STAGE_A(2); STAGE_B(2);
    asm volatile("s_waitcnt vmcnt(4)" ::: "memory");   // stages 0,1 landed; 2 in flight
    __builtin_amdgcn_s_barrier();
    asm volatile("" ::: "memory");
#pragma unroll
    for (int m = 0; m < 4; ++m)
        aC[m] = *(const bf16x8v*)((const char*)&lds[0][0] + aOff + m * 1024);
#pragma unroll
    for (int n = 0; n < 4; ++n)
        bX[n] = *(const bf16x8v*)((const char*)&lds[0][0] + bOff + n * 1024);

    // ---- main loop: pieces 0..123 (b-roles alternate by parity)
    for (int p = 0; p < NPIECE - 4; p += 2) {
        PIECE_BODY(p,     bX, bY, 1, 1, "s_waitcnt vmcnt(4)");
        PIECE_BODY(p + 1, bY, bX, 1, 1, "s_waitcnt vmcnt(4)");
    }
    // ---- tail: pieces 124..127 (stage(127) issued at 124; then drain)
    PIECE_BODY(124, bX, bY, 1, 1, "s_waitcnt vmcnt(4)");
    PIECE_BODY(125, bY, bX, 0, 1, "s_waitcnt vmcnt(0)");
    PIECE_BODY(126, bX, bY, 0, 1, "s_nop 0");
    PIECE_BODY(127, bY, bX, 0, 0, "s_nop 0");

#undef PIECE_BODY
#undef STAGE_A
#undef STAGE_B

    // ---- epilogue: C/D layout col=lane&15, row=(lane>>4)*4+j
    const int q   = lane >> 4;
    const int gr0 = bm * 256 + wm * 128;
    const int gc0 = bn * 256 + wn * 64 + r;
    float bv[4];
#pragma unroll
    for (int n = 0; n < 4; ++n) bv[n] = bias[gc0 + n * 16];
#pragma unroll
    for (int m = 0; m < 8; ++m)
#pragma unroll
        for (int j = 0; j < 4; ++j) {
            float* crow = C + (size_t)(gr0 + m * 16 + q * 4 + j) * N_DIM + gc0;
#pragma unroll
            for (int n = 0; n < 4; ++n)
                crow[n * 16] = acc[m][n][j] + bv[n];
        }
}

// ---------- naive fallback (only if ws too small)
__global__ void k_naive(const float* __restrict__ x, const int* __restrict__ qw,
                        const float* __restrict__ scales, const float* __restrict__ bias,
                        const float* __restrict__ lut, float* __restrict__ y) {
    long t = (long)blockIdx.x * blockDim.x + threadIdx.x;
    if (t >= (long)M_DIM * N_DIM) return;
    int m = (int)(t / N_DIM), n = (int)(t % N_DIM);
    float acc = 0.f;
    for (int k = 0; k < K_DIM; k += 2) {
        int b = qw[n * (K_DIM / 2) + (k >> 1)];
        float s = scales[n * 32 + (k >> 7)];
        acc += x[(size_t)m * K_DIM + k]     * lut[b & 15]        * s;
        acc += x[(size_t)m * K_DIM + k + 1] * lut[(b >> 4) & 15] * s;
    }
    y[t] = acc + bias[n];
}

extern "C" void kernel_launch(void* const* d_in, const int* in_sizes, int n_in,
                              void* d_out, int out_size, void* d_ws, size_t ws_size,
                              hipStream_t stream) {
    const float* x      = (const float*)d_in[0];
    const int*   qw     = (const int*)d_in[1];
    const float* scales = (const float*)d_in[2];
    const float* bias   = (const float*)d_in[3];
    const float* lut    = (const float*)d_in[5];
    float* y = (float*)d_out;

    const size_t wbBytes = (size_t)N_DIM * K_DIM * 2;   // 32 MiB
    const size_t xbBytes = (size_t)M_DIM * K_DIM * 2;   // 64 MiB
    if (ws_size < wbBytes + xbBytes) {
        long total = (long)M_DIM * N_DIM;
        k_naive<<<(int)((total + 255) / 256), 256, 0, stream>>>(x, qw, scales, bias, lut, y);
        return;
    }
    __hip_bfloat16* Wb = (__hip_bfloat16*)d_ws;
    __hip_bfloat16* Xb = (__hip_bfloat16*)((char*)d_ws + wbBytes);

    k_prep<<<DQ_BLOCKS + CVT_BLOCKS, 256, 0, stream>>>(
        (const int4*)qw, scales, lut, (uint4*)Wb, (const float4*)x, (uint4*)Xb);
    dim3 grid(N_DIM / 256, M_DIM / 256);
    k_gemm<<<grid, 512, 0, stream>>>(Xb, Wb, bias, y);
}